// Round 2
// baseline (309.077 us; speedup 1.0000x reference)
//
#include <hip/hip_runtime.h>
#include <hip/hip_bf16.h>

// ---------------------------------------------------------------------------
// Transformer block: x + attn(LN1(x)) ; then x2 + proj(relu(fc(LN2(x2))))
// B=2, T=2048, C=1024, H=16, hd=64, MLP hidden 4096. All GEMMs bf16 MFMA.
// R13: attn restructured: QK key-split across waves (each wave: all 64 q x
//      its 16 keys; kf reads 32->8/tile), shared sP[64][64] with XOR swizzle
//      col ^= ((row>>1)&7)<<3 (write banks exactly 2-way, pf b128 reads at
//      minimum 8 lanes/4-bank window -> conflicts ~0), mid-tile raw
//      lgkmcnt(0)+s_barrier (vmcnt untouched so K/V prefetch stays in
//      flight). PV + epilogue + V-swizzle unchanged. gemm256: MFMA emission
//      reordered K-outer (dep distance 8 instead of back-to-back).
// ---------------------------------------------------------------------------

typedef __bf16  bf16x8  __attribute__((ext_vector_type(8)));
typedef __bf16  bf16x4  __attribute__((ext_vector_type(4)));
typedef float   floatx4 __attribute__((ext_vector_type(4)));

#define T_LEN 2048
#define EMB   1024
#define NH    16
#define HD    64
#define HID   4096

#define GLOBAL_LOAD_LDS16(gp, lp) \
    __builtin_amdgcn_global_load_lds( \
        (const __attribute__((address_space(1))) void*)(gp), \
        (__attribute__((address_space(3))) void*)(lp), 16, 0, 0)

// ---------------- transpose + cast: in fp32 [R,C] -> out bf16 [C,R] --------
__global__ void transpose_cast(const float* __restrict__ in,
                               __bf16* __restrict__ out, int R, int C) {
    __shared__ float tile[32][33];
    int bc = blockIdx.x * 32;
    int br = blockIdx.y * 32;
    int tx = threadIdx.x;
    int ty = threadIdx.y;
    for (int i = 0; i < 32; i += 8) {
        tile[ty + i][tx] = in[(size_t)(br + ty + i) * C + bc + tx];
    }
    __syncthreads();
    for (int i = 0; i < 32; i += 8) {
        int c = bc + ty + i, r = br + tx;
        out[(size_t)c * R + r] = (__bf16)tile[tx][ty + i];
    }
}

// ---------------- layernorm fp32 [M,1024] -> bf16 [M,1024] -----------------
__global__ __launch_bounds__(256)
void ln_kernel(const float* __restrict__ in, const float* __restrict__ sc,
               const float* __restrict__ sh, __bf16* __restrict__ out) {
    int row = blockIdx.x;
    const float* p = in + (size_t)row * EMB;
    int tid = threadIdx.x;
    int lane = tid & 63, wave = tid >> 6;
    float v[4];
    float s = 0.f, s2 = 0.f;
    for (int j = 0; j < 4; j++) {
        v[j] = p[tid + j * 256];
        s += v[j]; s2 += v[j] * v[j];
    }
    for (int m = 1; m < 64; m <<= 1) {
        s  += __shfl_xor(s, m);
        s2 += __shfl_xor(s2, m);
    }
    __shared__ float ssum[4], ssum2[4];
    if (lane == 0) { ssum[wave] = s; ssum2[wave] = s2; }
    __syncthreads();
    float tot  = ssum[0] + ssum[1] + ssum[2] + ssum[3];
    float tot2 = ssum2[0] + ssum2[1] + ssum2[2] + ssum2[3];
    float mean = tot * (1.f / EMB);
    float var  = tot2 * (1.f / EMB) - mean * mean;
    float rstd = rsqrtf(var + 1e-5f);
    for (int j = 0; j < 4; j++) {
        int c = tid + j * 256;
        out[(size_t)row * EMB + c] = (__bf16)((v[j] - mean) * rstd * sc[c] + sh[c]);
    }
}

// ---------------- bf16 MFMA GEMM, BM=BN=256 BK=64, counted-vmcnt pipeline --
__global__ __launch_bounds__(512)
void gemm256(const __bf16* __restrict__ A, const __bf16* __restrict__ Bt,
             const float* __restrict__ bias, const float* __restrict__ res,
             float* __restrict__ outF, __bf16* __restrict__ outB,
             int M, int N, int lda, int KL, int relu, int gx, int gz) {
    __shared__ __align__(16) __bf16 sA[2][256][64];
    __shared__ __align__(16) __bf16 sB[2][256][64];
    const int BUFE = 256 * 64;
    int tid  = threadIdx.x;
    int lane = tid & 63, wave = tid >> 6;
    int quad = lane >> 4, l16 = lane & 15;

    // XCD swizzle decode: pair p=(by*gz+bz) pinned to XCD p&7. grid%8==0.
    int i  = blockIdx.x;
    int c  = i & 7, m = i >> 3;
    int bx = m % gx;
    int p  = (m / gx) * 8 + c;
    int by = p / gz;
    int bz = p - by * gz;

    int bm = by * 256, bn = bx * 256;
    size_t k0 = (size_t)bz * KL;
    int wm = (wave >> 2) * 128, wn = (wave & 3) * 64;

    floatx4 acc[8][4] = {};

    int srow  = tid >> 3;
    int sslot = (tid & 7) ^ (srow & 7);
    const __bf16* gA = A  + (size_t)(bm + srow) * lda + k0 + sslot * 8;
    const __bf16* gB = Bt + (size_t)(bn + srow) * lda + k0 + sslot * 8;
    __bf16* lA = &sA[0][0][0] + wave * 512;
    __bf16* lB = &sB[0][0][0] + wave * 512;
    const size_t rstep = (size_t)64 * lda;

#define STAGE256(nb, ko) do { \
    GLOBAL_LOAD_LDS16(gA + (ko),             lA + (nb) * BUFE); \
    GLOBAL_LOAD_LDS16(gB + (ko),             lB + (nb) * BUFE); \
    GLOBAL_LOAD_LDS16(gA + (ko) + rstep,     lA + (nb) * BUFE + 4096); \
    GLOBAL_LOAD_LDS16(gB + (ko) + rstep,     lB + (nb) * BUFE + 4096); \
    GLOBAL_LOAD_LDS16(gA + (ko) + 2 * rstep, lA + (nb) * BUFE + 8192); \
    GLOBAL_LOAD_LDS16(gB + (ko) + 2 * rstep, lB + (nb) * BUFE + 8192); \
    GLOBAL_LOAD_LDS16(gA + (ko) + 3 * rstep, lA + (nb) * BUFE + 12288); \
    GLOBAL_LOAD_LDS16(gB + (ko) + 3 * rstep, lB + (nb) * BUFE + 12288); \
} while (0)

    STAGE256(0, (size_t)0);

    int xs0  = ((quad) ^ (l16 & 7)) * 8;
    int xs1  = ((4 + quad) ^ (l16 & 7)) * 8;
    int aoff = (wm + l16) * 64;
    int boff = (wn + l16) * 64;

    const int nt = KL / 64;
    for (int t = 0; t < nt; ++t) {
        const int cur = t & 1;
        __builtin_amdgcn_s_barrier();          // all waves done reading buf^1
        asm volatile("" ::: "memory");
        if (t + 1 < nt) {
            STAGE256(cur ^ 1, (size_t)(t + 1) * 64);
            asm volatile("s_waitcnt vmcnt(8)" ::: "memory");  // tile t landed
        } else {
            asm volatile("s_waitcnt vmcnt(0)" ::: "memory");
        }
        __builtin_amdgcn_s_barrier();          // everyone's tile-t loads done
        asm volatile("" ::: "memory");
        __builtin_amdgcn_sched_barrier(0);

        const __bf16* sAc = &sA[0][0][0] + cur * BUFE;
        const __bf16* sBc = &sB[0][0][0] + cur * BUFE;

        bf16x8 a0[4][2], a1[4][2], b0[2][2], b1[2][2];

        // phase 1: A rows 0-63 (mi 0-3) + B cols 0-31 (nj 0-1)
        #pragma unroll
        for (int mi = 0; mi < 4; ++mi) {
            a0[mi][0] = *(const bf16x8*)(sAc + aoff + mi * 1024 + xs0);
            a0[mi][1] = *(const bf16x8*)(sAc + aoff + mi * 1024 + xs1);
        }
        #pragma unroll
        for (int nj = 0; nj < 2; ++nj) {
            b0[nj][0] = *(const bf16x8*)(sBc + boff + nj * 1024 + xs0);
            b0[nj][1] = *(const bf16x8*)(sBc + boff + nj * 1024 + xs1);
        }
        __builtin_amdgcn_s_setprio(1);
        #pragma unroll
        for (int ks = 0; ks < 2; ++ks)
            #pragma unroll
            for (int mi = 0; mi < 4; ++mi)
                #pragma unroll
                for (int nj = 0; nj < 2; ++nj)
                    acc[mi][nj] = __builtin_amdgcn_mfma_f32_16x16x32_bf16(
                        a0[mi][ks], b0[nj][ks], acc[mi][nj], 0, 0, 0);
        __builtin_amdgcn_s_setprio(0);

        // phase 2: load B cols 32-63 (nj 2-3); MFMA a0 x b1
        #pragma unroll
        for (int nj = 0; nj < 2; ++nj) {
            b1[nj][0] = *(const bf16x8*)(sBc + boff + (2 + nj) * 1024 + xs0);
            b1[nj][1] = *(const bf16x8*)(sBc + boff + (2 + nj) * 1024 + xs1);
        }
        __builtin_amdgcn_s_setprio(1);
        #pragma unroll
        for (int ks = 0; ks < 2; ++ks)
            #pragma unroll
            for (int mi = 0; mi < 4; ++mi)
                #pragma unroll
                for (int nj = 0; nj < 2; ++nj)
                    acc[mi][2 + nj] = __builtin_amdgcn_mfma_f32_16x16x32_bf16(
                        a0[mi][ks], b1[nj][ks], acc[mi][2 + nj], 0, 0, 0);
        __builtin_amdgcn_s_setprio(0);

        // phase 3: load A rows 64-127 (mi 4-7); MFMA a1 x b1
        #pragma unroll
        for (int mi = 0; mi < 4; ++mi) {
            a1[mi][0] = *(const bf16x8*)(sAc + aoff + (4 + mi) * 1024 + xs0);
            a1[mi][1] = *(const bf16x8*)(sAc + aoff + (4 + mi) * 1024 + xs1);
        }
        __builtin_amdgcn_s_setprio(1);
        #pragma unroll
        for (int ks = 0; ks < 2; ++ks)
            #pragma unroll
            for (int mi = 0; mi < 4; ++mi)
                #pragma unroll
                for (int nj = 0; nj < 2; ++nj)
                    acc[4 + mi][2 + nj] = __builtin_amdgcn_mfma_f32_16x16x32_bf16(
                        a1[mi][ks], b1[nj][ks], acc[4 + mi][2 + nj], 0, 0, 0);
        __builtin_amdgcn_s_setprio(0);

        // phase 4: MFMA a1 x b0 (no loads)
        __builtin_amdgcn_s_setprio(1);
        #pragma unroll
        for (int ks = 0; ks < 2; ++ks)
            #pragma unroll
            for (int mi = 0; mi < 4; ++mi)
                #pragma unroll
                for (int nj = 0; nj < 2; ++nj)
                    acc[4 + mi][nj] = __builtin_amdgcn_mfma_f32_16x16x32_bf16(
                        a1[mi][ks], b0[nj][ks], acc[4 + mi][nj], 0, 0, 0);
        __builtin_amdgcn_s_setprio(0);
    }
#undef STAGE256

    if (bias) {
        #pragma unroll
        for (int mi = 0; mi < 8; ++mi) {
            int row0 = bm + wm + mi * 16 + quad * 4;
            #pragma unroll
            for (int nj = 0; nj < 4; ++nj) {
                int col = bn + wn + nj * 16 + l16;
                float bv = bias[col];
                #pragma unroll
                for (int r = 0; r < 4; ++r) {
                    size_t idx = (size_t)(row0 + r) * N + col;
                    float cc = acc[mi][nj][r] + bv;
                    if (relu) cc = fmaxf(cc, 0.f);
                    if (res)  cc += res[idx];
                    if (outF) outF[idx] = cc;
                    if (outB) outB[idx] = (__bf16)cc;
                }
            }
        }
    } else {
        __bf16* po = outB + (size_t)bz * M * N;
        #pragma unroll
        for (int mi = 0; mi < 8; ++mi) {
            int row0 = bm + wm + mi * 16 + quad * 4;
            #pragma unroll
            for (int nj = 0; nj < 4; ++nj) {
                int col = bn + wn + nj * 16 + l16;
                #pragma unroll
                for (int r = 0; r < 4; ++r)
                    po[(size_t)(row0 + r) * N + col] = (__bf16)acc[mi][nj][r];
            }
        }
    }
}

// ---------------- split-K reduce: out = x2 + bias + sum of 4 bf16 partials -
__global__ __launch_bounds__(256)
void reduce_proj(const __bf16* __restrict__ pbuf, const float* __restrict__ x2,
                 const float* __restrict__ bias, float* __restrict__ out) {
    const size_t MN = (size_t)4096 * 1024;
    size_t i = (size_t)blockIdx.x * 256 + threadIdx.x;   // float4 index
    float4 r = ((const float4*)x2)[i];
    float4 bb = ((const float4*)bias)[i & 255];
    float acc0 = r.x + bb.x, acc1 = r.y + bb.y;
    float acc2 = r.z + bb.z, acc3 = r.w + bb.w;
    for (int k = 0; k < 4; k++) {
        bf16x4 pv = *(const bf16x4*)&pbuf[k * MN + i * 4];
        acc0 += (float)pv[0]; acc1 += (float)pv[1];
        acc2 += (float)pv[2]; acc3 += (float)pv[3];
    }
    float4 o = {acc0, acc1, acc2, acc3};
    ((float4*)out)[i] = o;
}

// ---------------- bf16 MFMA GEMM (BM=128, BN=64) — ws-fallback only --------
__global__ __launch_bounds__(256)
void gemm_bt_n64(const __bf16* __restrict__ A, const __bf16* __restrict__ Bt,
                 const float* __restrict__ bias, const float* __restrict__ res,
                 float* __restrict__ outF, __bf16* __restrict__ outB,
                 int M, int N, int K, int relu) {
    __shared__ __align__(16) __bf16 sA[128][40];
    __shared__ __align__(16) __bf16 sB[64][40];
    int tid  = threadIdx.x;
    int lane = tid & 63, wave = tid >> 6;
    int quad = lane >> 4, l16 = lane & 15;
    int bm = blockIdx.y * 128, bn = blockIdx.x * 64;
    int wm = (wave & 1) * 64, wn = (wave >> 1) * 32;
    floatx4 acc[4][2] = {};

    int srow = tid >> 2;
    int scol = (tid & 3) * 8;
    const __bf16* gA = &A[(size_t)(bm + srow) * K + scol];
    const __bf16* gB = &Bt[(size_t)(bn + srow) * K + scol];

    uint4 ra0 = *(const uint4*)gA;
    uint4 ra1 = *(const uint4*)(gA + (size_t)64 * K);
    uint4 rb0 = *(const uint4*)gB;

    for (int kk = 0; kk < K; kk += 32) {
        __syncthreads();
        *(uint4*)&sA[srow][scol]      = ra0;
        *(uint4*)&sA[srow + 64][scol] = ra1;
        *(uint4*)&sB[srow][scol]      = rb0;
        __syncthreads();
        {
            int kn = (kk + 32 < K) ? kk + 32 : kk;
            ra0 = *(const uint4*)(gA + kn);
            ra1 = *(const uint4*)(gA + kn + (size_t)64 * K);
            rb0 = *(const uint4*)(gB + kn);
        }
        bf16x8 af[4], bfr[2];
        for (int i = 0; i < 4; i++)
            af[i] = *(const bf16x8*)&sA[wm + i * 16 + l16][quad * 8];
        for (int j = 0; j < 2; j++)
            bfr[j] = *(const bf16x8*)&sB[wn + j * 16 + l16][quad * 8];
        for (int i = 0; i < 4; i++)
            for (int j = 0; j < 2; j++)
                acc[i][j] = __builtin_amdgcn_mfma_f32_16x16x32_bf16(
                    af[i], bfr[j], acc[i][j], 0, 0, 0);
    }

    for (int i = 0; i < 4; i++) {
        int row0 = bm + wm + i * 16 + quad * 4;
        for (int j = 0; j < 2; j++) {
            int col = bn + wn + j * 16 + l16;
            float bv = bias[col];
            for (int r = 0; r < 4; r++) {
                size_t idx = (size_t)(row0 + r) * N + col;
                float c = acc[i][j][r] + bv;
                if (relu) c = fmaxf(c, 0.f);
                if (res)  c += res[idx];
                if (outF) outF[idx] = c;
                if (outB) outB[idx] = (__bf16)c;
            }
        }
    }
}

// ---------------- flash attention: dbuf, fixed-max, QK key-split -----------
// grid 1024: i -> XCD c=i&7, m=i>>3; bh=(m&3)*8+c (pinned to XCD);
// qb = 31 - (m>>2) (heavy first). Softmax: P = exp2(min(s,30)) fixed-max.
// QK: wave w computes S for ALL 64 q-rows x keys [w*16, w*16+16) (kf reads
// 8/tile instead of 32). P exchanged via shared sP[64][64], XOR-swizzled
// col ^= ((row>>1)&7)<<3 -> conflict-free writes & b128 reads. PV: wave owns
// q-range wave*16 (unchanged). l via ones-MFMA; epilogue divides.
__global__ __launch_bounds__(256)
void attn_kernel(const __bf16* __restrict__ qkv, const float* __restrict__ x,
                 float* __restrict__ x2) {
    __shared__ __align__(16) __bf16 sK[2][64][72];
    __shared__ __align__(16) __bf16 sVt[2][64][72];
    __shared__ __align__(16) __bf16 sP[64][64];
    const int tid  = threadIdx.x;
    const int lane = tid & 63, wave = tid >> 6;
    const int quad = lane >> 4, l16 = lane & 15;

    int i = blockIdx.x;
    int c = i & 7, m = i >> 3;
    const int bh = (m & 3) * 8 + c;            // 0..31, XCD-pinned
    const int qb = 31 - (m >> 2);              // heavy first
    const int h  = bh & (NH - 1);
    const int b  = bh >> 4;
    const size_t rowbase = (size_t)b * T_LEN;
    const int qrow = qb * 64 + wave * 16;      // PV q-range (unchanged)

    const float kQScale = 0.125f * 1.44269504088896f;
    bf16x8 ones;
    for (int j = 0; j < 8; j++) ones[j] = (__bf16)1.0f;

    const int key0 = tid >> 3, m8 = tid & 7;
    const int key1 = key0 + 32;
    const __bf16* kp0 = qkv + (rowbase + key0) * 3072 + h * HD + m8 * 8 + 1024;
    const __bf16* kp1 = qkv + (rowbase + key1) * 3072 + h * HD + m8 * 8 + 1024;
    const int pc0 = ((key0 >> 3) ^ m8) * 8 + (key0 & 7);
    const int pc1 = ((key1 >> 3) ^ m8) * 8 + (key1 & 7);

    // Q fragments for ALL 64 q-rows of this q-block (QK key-split needs them)
    bf16x8 qf[4][2];
    for (int qi = 0; qi < 4; qi++)
        for (int ks = 0; ks < 2; ks++) {
            bf16x8 raw = *(const bf16x8*)&qkv[(rowbase + qb * 64 + qi * 16 + l16)
                                              * 3072 + h * HD + ks * 32 + quad * 8];
            for (int j = 0; j < 8; j++)
                qf[qi][ks][j] = (__bf16)((float)raw[j] * kQScale);
        }

    floatx4 o[4] = {}, ol = {};

    const int ntiles = qb + 1;
    const size_t TSTEP = (size_t)64 * 3072;

    // prologue: tile 0 -> regs -> buf0 ; tile 1 -> regs ; barrier
    uint4 kr0 = *(const uint4*)kp0;
    uint4 kr1 = *(const uint4*)kp1;
    uint4 vr0 = *(const uint4*)(kp0 + 1024);
    uint4 vr1 = *(const uint4*)(kp1 + 1024);
    {
        *(uint4*)&sK[0][key0][m8 * 8] = kr0;
        *(uint4*)&sK[0][key1][m8 * 8] = kr1;
        bf16x8 v0 = *(bf16x8*)&vr0, v1 = *(bf16x8*)&vr1;
        for (int j = 0; j < 8; j++) sVt[0][m8 * 8 + j][pc0] = v0[j];
        for (int j = 0; j < 8; j++) sVt[0][m8 * 8 + j][pc1] = v1[j];
    }
    {
        size_t o1 = (ntiles > 1) ? TSTEP : 0;
        kr0 = *(const uint4*)(kp0 + o1);
        kr1 = *(const uint4*)(kp1 + o1);
        vr0 = *(const uint4*)(kp0 + o1 + 1024);
        vr1 = *(const uint4*)(kp1 + o1 + 1024);
    }
    __syncthreads();

    for (int kt = 0; kt < ntiles; kt++) {
        const int cur = kt & 1, nxt = cur ^ 1;
        if (kt + 1 < ntiles) {
            *(uint4*)&sK[nxt][key0][m8 * 8] = kr0;
            *(uint4*)&sK[nxt][key1][m8 * 8] = kr1;
            bf16x8 v0 = *(bf16x8*)&vr0, v1 = *(bf16x8*)&vr1;
            for (int j = 0; j < 8; j++) sVt[nxt][m8 * 8 + j][pc0] = v0[j];
            for (int j = 0; j < 8; j++) sVt[nxt][m8 * 8 + j][pc1] = v1[j];
            size_t offn = (size_t)((kt + 2 < ntiles) ? kt + 2 : kt + 1) * TSTEP;
            kr0 = *(const uint4*)(kp0 + offn);
            kr1 = *(const uint4*)(kp1 + offn);
            vr0 = *(const uint4*)(kp0 + offn + 1024);
            vr1 = *(const uint4*)(kp1 + offn + 1024);
        }

        // S = Q K^T (exp2 domain): ALL 64 q-rows x this wave's 16 keys
        floatx4 s_acc[4] = {};
        for (int ks = 0; ks < 2; ks++) {
            bf16x8 kf = *(const bf16x8*)&sK[cur][wave * 16 + l16]
                                          [ks * 32 + quad * 8];
            for (int qi = 0; qi < 4; qi++)
                s_acc[qi] = __builtin_amdgcn_mfma_f32_16x16x32_bf16(
                    qf[qi][ks], kf, s_acc[qi], 0, 0, 0);
        }

        // P = exp2(min(s,30)); mask only on diagonal tile.
        // write sP[row=q][col = k ^ ((row>>1 & 7)<<3)] -> conflict-free.
        const int kk = wave * 16 + l16;        // key within tile
        if (kt == qb) {
            for (int qi = 0; qi < 4; qi++)
                for (int r = 0; r < 4; r++) {
                    int tq = qi * 16 + quad * 4 + r;
                    float sv = (kk <= tq) ? s_acc[qi][r] : -1e30f;
                    float pv = __builtin_amdgcn_exp2f(fminf(sv, 30.f));
                    sP[tq][kk ^ ((quad * 2 + (r >> 1)) << 3)] = (__bf16)pv;
                }
        } else {
            for (int qi = 0; qi < 4; qi++)
                for (int r = 0; r < 4; r++) {
                    float pv = __builtin_amdgcn_exp2f(fminf(s_acc[qi][r], 30.f));
                    sP[qi * 16 + quad * 4 + r]
                      [kk ^ ((quad * 2 + (r >> 1)) << 3)] = (__bf16)pv;
                }
        }

        // mid-tile barrier: sP now cross-wave. Raw lgkmcnt(0)+s_barrier so
        // the global K/V prefetch (vmcnt) stays in flight.
        asm volatile("s_waitcnt lgkmcnt(0)" ::: "memory");
        __builtin_amdgcn_s_barrier();
        asm volatile("" ::: "memory");

        for (int kp = 0; kp < 2; kp++) {
            bf16x8 pf = *(const bf16x8*)&sP[wave * 16 + l16]
                          [(kp * 32 + quad * 8) ^ ((l16 >> 1) << 3)];
            ol = __builtin_amdgcn_mfma_f32_16x16x32_bf16(pf, ones, ol, 0, 0, 0);
            for (int jt2 = 0; jt2 < 4; jt2++) {
                int d = jt2 * 16 + l16;
                int pg = (kp * 4 + quad) ^ (d >> 3);
                bf16x8 vf = *(const bf16x8*)&sVt[cur][d][pg * 8];
                o[jt2] = __builtin_amdgcn_mfma_f32_16x16x32_bf16(
                    pf, vf, o[jt2], 0, 0, 0);
            }
        }
        __syncthreads();   // all waves done reading cur/sP & writing nxt
    }

    float inv[4];
    for (int r = 0; r < 4; r++) inv[r] = __builtin_amdgcn_rcpf(ol[r]);
    for (int jt2 = 0; jt2 < 4; jt2++) {
        for (int r = 0; r < 4; r++) {
            int tq  = qrow + quad * 4 + r;
            int col = h * HD + jt2 * 16 + l16;
            size_t gi = (rowbase + tq) * EMB + col;
            x2[gi] = x[gi] + o[jt2][r] * inv[r];
        }
    }
}

// ---------------------------------------------------------------------------
extern "C" void kernel_launch(void* const* d_in, const int* in_sizes, int n_in,
                              void* d_out, int out_size, void* d_ws, size_t ws_size,
                              hipStream_t stream) {
    const float* x      = (const float*)d_in[0];
    const float* ln1_s  = (const float*)d_in[1];
    const float* ln1_b  = (const float*)d_in[2];
    const float* w_qkv  = (const float*)d_in[3];
    const float* b_qkv  = (const float*)d_in[4];
    const float* ln2_s  = (const float*)d_in[5];
    const float* ln2_b  = (const float*)d_in[6];
    const float* w_fc   = (const float*)d_in[7];
    const float* b_fc   = (const float*)d_in[8];
    const float* w_proj = (const float*)d_in[9];
    const float* b_proj = (const float*)d_in[10];
    float* out = (float*)d_out;

    const int M = 2 * T_LEN;  // 4096 rows
    char* ws = (char*)d_ws;
    size_t off = 0;
    auto alloc = [&](size_t bytes) {
        void* p = ws + off; off += (bytes + 255) & ~(size_t)255; return p;
    };
    // alive through proj:
    __bf16* wpj_t  = (__bf16*)alloc((size_t)1024 * 4096 * 2);
    float*  x2     = (float*) alloc((size_t)M * 1024 * 4);
    __bf16* hfc    = (__bf16*)alloc((size_t)M * 4096 * 2);
    size_t mark = off;                    // dead-by-proj region starts here
    __bf16* wqkv_t = (__bf16*)alloc((size_t)3072 * 1024 * 2);
    __bf16* wfc_t  = (__bf16*)alloc((size_t)4096 * 1024 * 2);
    __bf16* h1     = (__bf16*)alloc((size_t)M * 1024 * 2);
    __bf16* h2     = (__bf16*)alloc((size_t)M * 1024 * 2);
    __bf16* qkvb   = (__bf16*)alloc((size_t)M * 3072 * 2);
    // split-K bf16 partials overlay the dead region.
    __bf16* pbuf = (__bf16*)(ws + mark);
    size_t need = mark + (size_t)4 * M * 1024 * 2;
    bool can_split = ws_size >= need;

    dim3 tb(32, 8);
    transpose_cast<<<dim3(3072 / 32, 1024 / 32), tb, 0, stream>>>(w_qkv, wqkv_t, 1024, 3072);
    transpose_cast<<<dim3(4096 / 32, 1024 / 32), tb, 0, stream>>>(w_fc,  wfc_t,  1024, 4096);
    transpose_cast<<<dim3(1024 / 32, 4096 / 32), tb, 0, stream>>>(w_proj, wpj_t, 4096, 1024);

    ln_kernel<<<M, 256, 0, stream>>>(x, ln1_s, ln1_b, h1);

    // qkv = LN1(x) @ w_qkv + b_qkv -> bf16 ; grid 16x12 flattened (192)
    gemm256<<<192, 512, 0, stream>>>(
        h1, wqkv_t, b_qkv, nullptr, nullptr, qkvb, M, 3072, 1024, 1024, 0,
        12, 1);

    attn_kernel<<<1024, 256, 0, stream>>>(qkvb, x, x2);

    ln_kernel<<<M, 256, 0, stream>>>(x2, ln2_s, ln2_b, h2);

    // hfc = relu(h2 @ w_fc + b_fc) -> bf16 ; grid 16x16 flattened (256)
    gemm256<<<256, 512, 0, stream>>>(
        h2, wfc_t, b_fc, nullptr, nullptr, hfc, M, 4096, 1024, 1024, 1,
        16, 1);

    if (can_split) {
        // proj partials: 4 K-chunks of 1024, grid 16x4x4 flattened (256)
        gemm256<<<256, 512, 0, stream>>>(
            hfc, wpj_t, nullptr, nullptr, nullptr, pbuf, M, 1024, 4096, 1024, 0,
            4, 4);
        reduce_proj<<<(M * 1024 / 4) / 256, 256, 0, stream>>>(
            pbuf, x2, b_proj, out);
    } else {
        gemm_bt_n64<<<dim3(1024 / 64, M / 128), 256, 0, stream>>>(
            hfc, wpj_t, b_proj, x2, out, nullptr, M, 1024, 4096, 0);
    }
}

// Round 4
// 304.367 us; speedup vs baseline: 1.0155x; 1.0155x over previous
//
#include <hip/hip_runtime.h>
#include <hip/hip_bf16.h>

// ---------------------------------------------------------------------------
// Transformer block: x + attn(LN1(x)) ; then x2 + proj(relu(fc(LN2(x2))))
// B=2, T=2048, C=1024, H=16, hd=64, MLP hidden 4096. All GEMMs bf16 MFMA.
// R14 (resubmit; prior round was an infra failure, no data): attn QBLK=128,
//      8 waves/block (512 thr). Wave-private softmax (R11 structure, no mid
//      barrier; conflicts proven non-critical in R13). Waves 0-3 diag tile =
//      2qbp, waves 4-7 = 2qbp+1; masked-out tiles skipped (barriers kept).
//      Block-tiles 16896->8704: staging, barriers, K/V refetch all halve.
//      LDS 55.3KB -> 2 blocks/CU = 16 waves/CU. Grid 512 = exactly 2/CU,
//      heavy-first, XCD-pinned. GEMMs unchanged.
// ---------------------------------------------------------------------------

typedef __bf16  bf16x8  __attribute__((ext_vector_type(8)));
typedef __bf16  bf16x4  __attribute__((ext_vector_type(4)));
typedef float   floatx4 __attribute__((ext_vector_type(4)));

#define T_LEN 2048
#define EMB   1024
#define NH    16
#define HD    64
#define HID   4096

#define GLOBAL_LOAD_LDS16(gp, lp) \
    __builtin_amdgcn_global_load_lds( \
        (const __attribute__((address_space(1))) void*)(gp), \
        (__attribute__((address_space(3))) void*)(lp), 16, 0, 0)

// ---------------- transpose + cast: in fp32 [R,C] -> out bf16 [C,R] --------
__global__ void transpose_cast(const float* __restrict__ in,
                               __bf16* __restrict__ out, int R, int C) {
    __shared__ float tile[32][33];
    int bc = blockIdx.x * 32;
    int br = blockIdx.y * 32;
    int tx = threadIdx.x;
    int ty = threadIdx.y;
    for (int i = 0; i < 32; i += 8) {
        tile[ty + i][tx] = in[(size_t)(br + ty + i) * C + bc + tx];
    }
    __syncthreads();
    for (int i = 0; i < 32; i += 8) {
        int c = bc + ty + i, r = br + tx;
        out[(size_t)c * R + r] = (__bf16)tile[tx][ty + i];
    }
}

// ---------------- layernorm fp32 [M,1024] -> bf16 [M,1024] -----------------
__global__ __launch_bounds__(256)
void ln_kernel(const float* __restrict__ in, const float* __restrict__ sc,
               const float* __restrict__ sh, __bf16* __restrict__ out) {
    int row = blockIdx.x;
    const float* p = in + (size_t)row * EMB;
    int tid = threadIdx.x;
    int lane = tid & 63, wave = tid >> 6;
    float v[4];
    float s = 0.f, s2 = 0.f;
    for (int j = 0; j < 4; j++) {
        v[j] = p[tid + j * 256];
        s += v[j]; s2 += v[j] * v[j];
    }
    for (int m = 1; m < 64; m <<= 1) {
        s  += __shfl_xor(s, m);
        s2 += __shfl_xor(s2, m);
    }
    __shared__ float ssum[4], ssum2[4];
    if (lane == 0) { ssum[wave] = s; ssum2[wave] = s2; }
    __syncthreads();
    float tot  = ssum[0] + ssum[1] + ssum[2] + ssum[3];
    float tot2 = ssum2[0] + ssum2[1] + ssum2[2] + ssum2[3];
    float mean = tot * (1.f / EMB);
    float var  = tot2 * (1.f / EMB) - mean * mean;
    float rstd = rsqrtf(var + 1e-5f);
    for (int j = 0; j < 4; j++) {
        int c = tid + j * 256;
        out[(size_t)row * EMB + c] = (__bf16)((v[j] - mean) * rstd * sc[c] + sh[c]);
    }
}

// ---------------- bf16 MFMA GEMM, BM=BN=256 BK=64, counted-vmcnt pipeline --
__global__ __launch_bounds__(512)
void gemm256(const __bf16* __restrict__ A, const __bf16* __restrict__ Bt,
             const float* __restrict__ bias, const float* __restrict__ res,
             float* __restrict__ outF, __bf16* __restrict__ outB,
             int M, int N, int lda, int KL, int relu, int gx, int gz) {
    __shared__ __align__(16) __bf16 sA[2][256][64];
    __shared__ __align__(16) __bf16 sB[2][256][64];
    const int BUFE = 256 * 64;
    int tid  = threadIdx.x;
    int lane = tid & 63, wave = tid >> 6;
    int quad = lane >> 4, l16 = lane & 15;

    // XCD swizzle decode: pair p=(by*gz+bz) pinned to XCD p&7. grid%8==0.
    int i  = blockIdx.x;
    int c  = i & 7, m = i >> 3;
    int bx = m % gx;
    int p  = (m / gx) * 8 + c;
    int by = p / gz;
    int bz = p - by * gz;

    int bm = by * 256, bn = bx * 256;
    size_t k0 = (size_t)bz * KL;
    int wm = (wave >> 2) * 128, wn = (wave & 3) * 64;

    floatx4 acc[8][4] = {};

    int srow  = tid >> 3;
    int sslot = (tid & 7) ^ (srow & 7);
    const __bf16* gA = A  + (size_t)(bm + srow) * lda + k0 + sslot * 8;
    const __bf16* gB = Bt + (size_t)(bn + srow) * lda + k0 + sslot * 8;
    __bf16* lA = &sA[0][0][0] + wave * 512;
    __bf16* lB = &sB[0][0][0] + wave * 512;
    const size_t rstep = (size_t)64 * lda;

#define STAGE256(nb, ko) do { \
    GLOBAL_LOAD_LDS16(gA + (ko),             lA + (nb) * BUFE); \
    GLOBAL_LOAD_LDS16(gB + (ko),             lB + (nb) * BUFE); \
    GLOBAL_LOAD_LDS16(gA + (ko) + rstep,     lA + (nb) * BUFE + 4096); \
    GLOBAL_LOAD_LDS16(gB + (ko) + rstep,     lB + (nb) * BUFE + 4096); \
    GLOBAL_LOAD_LDS16(gA + (ko) + 2 * rstep, lA + (nb) * BUFE + 8192); \
    GLOBAL_LOAD_LDS16(gB + (ko) + 2 * rstep, lB + (nb) * BUFE + 8192); \
    GLOBAL_LOAD_LDS16(gA + (ko) + 3 * rstep, lA + (nb) * BUFE + 12288); \
    GLOBAL_LOAD_LDS16(gB + (ko) + 3 * rstep, lB + (nb) * BUFE + 12288); \
} while (0)

    STAGE256(0, (size_t)0);

    int xs0  = ((quad) ^ (l16 & 7)) * 8;
    int xs1  = ((4 + quad) ^ (l16 & 7)) * 8;
    int aoff = (wm + l16) * 64;
    int boff = (wn + l16) * 64;

    const int nt = KL / 64;
    for (int t = 0; t < nt; ++t) {
        const int cur = t & 1;
        __builtin_amdgcn_s_barrier();          // all waves done reading buf^1
        asm volatile("" ::: "memory");
        if (t + 1 < nt) {
            STAGE256(cur ^ 1, (size_t)(t + 1) * 64);
            asm volatile("s_waitcnt vmcnt(8)" ::: "memory");  // tile t landed
        } else {
            asm volatile("s_waitcnt vmcnt(0)" ::: "memory");
        }
        __builtin_amdgcn_s_barrier();          // everyone's tile-t loads done
        asm volatile("" ::: "memory");
        __builtin_amdgcn_sched_barrier(0);

        const __bf16* sAc = &sA[0][0][0] + cur * BUFE;
        const __bf16* sBc = &sB[0][0][0] + cur * BUFE;

        bf16x8 a0[4][2], a1[4][2], b0[2][2], b1[2][2];

        // phase 1: A rows 0-63 (mi 0-3) + B cols 0-31 (nj 0-1)
        #pragma unroll
        for (int mi = 0; mi < 4; ++mi) {
            a0[mi][0] = *(const bf16x8*)(sAc + aoff + mi * 1024 + xs0);
            a0[mi][1] = *(const bf16x8*)(sAc + aoff + mi * 1024 + xs1);
        }
        #pragma unroll
        for (int nj = 0; nj < 2; ++nj) {
            b0[nj][0] = *(const bf16x8*)(sBc + boff + nj * 1024 + xs0);
            b0[nj][1] = *(const bf16x8*)(sBc + boff + nj * 1024 + xs1);
        }
        __builtin_amdgcn_s_setprio(1);
        #pragma unroll
        for (int ks = 0; ks < 2; ++ks)
            #pragma unroll
            for (int mi = 0; mi < 4; ++mi)
                #pragma unroll
                for (int nj = 0; nj < 2; ++nj)
                    acc[mi][nj] = __builtin_amdgcn_mfma_f32_16x16x32_bf16(
                        a0[mi][ks], b0[nj][ks], acc[mi][nj], 0, 0, 0);
        __builtin_amdgcn_s_setprio(0);

        // phase 2: load B cols 32-63 (nj 2-3); MFMA a0 x b1
        #pragma unroll
        for (int nj = 0; nj < 2; ++nj) {
            b1[nj][0] = *(const bf16x8*)(sBc + boff + (2 + nj) * 1024 + xs0);
            b1[nj][1] = *(const bf16x8*)(sBc + boff + (2 + nj) * 1024 + xs1);
        }
        __builtin_amdgcn_s_setprio(1);
        #pragma unroll
        for (int ks = 0; ks < 2; ++ks)
            #pragma unroll
            for (int mi = 0; mi < 4; ++mi)
                #pragma unroll
                for (int nj = 0; nj < 2; ++nj)
                    acc[mi][2 + nj] = __builtin_amdgcn_mfma_f32_16x16x32_bf16(
                        a0[mi][ks], b1[nj][ks], acc[mi][2 + nj], 0, 0, 0);
        __builtin_amdgcn_s_setprio(0);

        // phase 3: load A rows 64-127 (mi 4-7); MFMA a1 x b1
        #pragma unroll
        for (int mi = 0; mi < 4; ++mi) {
            a1[mi][0] = *(const bf16x8*)(sAc + aoff + (4 + mi) * 1024 + xs0);
            a1[mi][1] = *(const bf16x8*)(sAc + aoff + (4 + mi) * 1024 + xs1);
        }
        __builtin_amdgcn_s_setprio(1);
        #pragma unroll
        for (int ks = 0; ks < 2; ++ks)
            #pragma unroll
            for (int mi = 0; mi < 4; ++mi)
                #pragma unroll
                for (int nj = 0; nj < 2; ++nj)
                    acc[4 + mi][2 + nj] = __builtin_amdgcn_mfma_f32_16x16x32_bf16(
                        a1[mi][ks], b1[nj][ks], acc[4 + mi][2 + nj], 0, 0, 0);
        __builtin_amdgcn_s_setprio(0);

        // phase 4: MFMA a1 x b0 (no loads)
        __builtin_amdgcn_s_setprio(1);
        #pragma unroll
        for (int ks = 0; ks < 2; ++ks)
            #pragma unroll
            for (int mi = 0; mi < 4; ++mi)
                #pragma unroll
                for (int nj = 0; nj < 2; ++nj)
                    acc[4 + mi][nj] = __builtin_amdgcn_mfma_f32_16x16x32_bf16(
                        a1[mi][ks], b0[nj][ks], acc[4 + mi][nj], 0, 0, 0);
        __builtin_amdgcn_s_setprio(0);
    }
#undef STAGE256

    if (bias) {
        #pragma unroll
        for (int mi = 0; mi < 8; ++mi) {
            int row0 = bm + wm + mi * 16 + quad * 4;
            #pragma unroll
            for (int nj = 0; nj < 4; ++nj) {
                int col = bn + wn + nj * 16 + l16;
                float bv = bias[col];
                #pragma unroll
                for (int r = 0; r < 4; ++r) {
                    size_t idx = (size_t)(row0 + r) * N + col;
                    float cc = acc[mi][nj][r] + bv;
                    if (relu) cc = fmaxf(cc, 0.f);
                    if (res)  cc += res[idx];
                    if (outF) outF[idx] = cc;
                    if (outB) outB[idx] = (__bf16)cc;
                }
            }
        }
    } else {
        __bf16* po = outB + (size_t)bz * M * N;
        #pragma unroll
        for (int mi = 0; mi < 8; ++mi) {
            int row0 = bm + wm + mi * 16 + quad * 4;
            #pragma unroll
            for (int nj = 0; nj < 4; ++nj) {
                int col = bn + wn + nj * 16 + l16;
                #pragma unroll
                for (int r = 0; r < 4; ++r)
                    po[(size_t)(row0 + r) * N + col] = (__bf16)acc[mi][nj][r];
            }
        }
    }
}

// ---------------- split-K reduce: out = x2 + bias + sum of 4 bf16 partials -
__global__ __launch_bounds__(256)
void reduce_proj(const __bf16* __restrict__ pbuf, const float* __restrict__ x2,
                 const float* __restrict__ bias, float* __restrict__ out) {
    const size_t MN = (size_t)4096 * 1024;
    size_t i = (size_t)blockIdx.x * 256 + threadIdx.x;   // float4 index
    float4 r = ((const float4*)x2)[i];
    float4 bb = ((const float4*)bias)[i & 255];
    float acc0 = r.x + bb.x, acc1 = r.y + bb.y;
    float acc2 = r.z + bb.z, acc3 = r.w + bb.w;
    for (int k = 0; k < 4; k++) {
        bf16x4 pv = *(const bf16x4*)&pbuf[k * MN + i * 4];
        acc0 += (float)pv[0]; acc1 += (float)pv[1];
        acc2 += (float)pv[2]; acc3 += (float)pv[3];
    }
    float4 o = {acc0, acc1, acc2, acc3};
    ((float4*)out)[i] = o;
}

// ---------------- bf16 MFMA GEMM (BM=128, BN=64) — ws-fallback only --------
__global__ __launch_bounds__(256)
void gemm_bt_n64(const __bf16* __restrict__ A, const __bf16* __restrict__ Bt,
                 const float* __restrict__ bias, const float* __restrict__ res,
                 float* __restrict__ outF, __bf16* __restrict__ outB,
                 int M, int N, int K, int relu) {
    __shared__ __align__(16) __bf16 sA[128][40];
    __shared__ __align__(16) __bf16 sB[64][40];
    int tid  = threadIdx.x;
    int lane = tid & 63, wave = tid >> 6;
    int quad = lane >> 4, l16 = lane & 15;
    int bm = blockIdx.y * 128, bn = blockIdx.x * 64;
    int wm = (wave & 1) * 64, wn = (wave >> 1) * 32;
    floatx4 acc[4][2] = {};

    int srow = tid >> 2;
    int scol = (tid & 3) * 8;
    const __bf16* gA = &A[(size_t)(bm + srow) * K + scol];
    const __bf16* gB = &Bt[(size_t)(bn + srow) * K + scol];

    uint4 ra0 = *(const uint4*)gA;
    uint4 ra1 = *(const uint4*)(gA + (size_t)64 * K);
    uint4 rb0 = *(const uint4*)gB;

    for (int kk = 0; kk < K; kk += 32) {
        __syncthreads();
        *(uint4*)&sA[srow][scol]      = ra0;
        *(uint4*)&sA[srow + 64][scol] = ra1;
        *(uint4*)&sB[srow][scol]      = rb0;
        __syncthreads();
        {
            int kn = (kk + 32 < K) ? kk + 32 : kk;
            ra0 = *(const uint4*)(gA + kn);
            ra1 = *(const uint4*)(gA + kn + (size_t)64 * K);
            rb0 = *(const uint4*)(gB + kn);
        }
        bf16x8 af[4], bfr[2];
        for (int i = 0; i < 4; i++)
            af[i] = *(const bf16x8*)&sA[wm + i * 16 + l16][quad * 8];
        for (int j = 0; j < 2; j++)
            bfr[j] = *(const bf16x8*)&sB[wn + j * 16 + l16][quad * 8];
        for (int i = 0; i < 4; i++)
            for (int j = 0; j < 2; j++)
                acc[i][j] = __builtin_amdgcn_mfma_f32_16x16x32_bf16(
                    af[i], bfr[j], acc[i][j], 0, 0, 0);
    }

    for (int i = 0; i < 4; i++) {
        int row0 = bm + wm + i * 16 + quad * 4;
        for (int j = 0; j < 2; j++) {
            int col = bn + wn + j * 16 + l16;
            float bv = bias[col];
            for (int r = 0; r < 4; r++) {
                size_t idx = (size_t)(row0 + r) * N + col;
                float c = acc[i][j][r] + bv;
                if (relu) c = fmaxf(c, 0.f);
                if (res)  c += res[idx];
                if (outF) outF[idx] = c;
                if (outB) outB[idx] = (__bf16)c;
            }
        }
    }
}

// ---------------- flash attention: QBLK=128, 8 waves, dbuf, fixed-max ------
// grid 512: i -> XCD c=i&7, m=i>>3; bh=(m&3)*8+c (pinned to XCD);
// qbp = 15-(m>>2) (heavy first), q rows [qbp*128, qbp*128+128).
// Wave w owns q rows qbp*128 + w*16..+16; diag tile dt = 2qbp + (w>=4);
// tiles > dt skipped (barriers kept). Softmax: P = exp2(min(s,30)) fixed-max,
// wave-private sP (no mid barrier). l via ones-MFMA; epilogue divides.
__global__ __launch_bounds__(512)
void attn_kernel(const __bf16* __restrict__ qkv, const float* __restrict__ x,
                 float* __restrict__ x2) {
    __shared__ __align__(16) __bf16 sK[2][64][72];
    __shared__ __align__(16) __bf16 sVt[2][64][72];
    __shared__ __align__(16) __bf16 sP[8][16][72];
    const int tid  = threadIdx.x;
    const int lane = tid & 63, wave = tid >> 6;
    const int quad = lane >> 4, l16 = lane & 15;

    int i = blockIdx.x;
    int c = i & 7, m = i >> 3;
    const int bh  = (m & 3) * 8 + c;           // 0..31, XCD-pinned
    const int qbp = 15 - (m >> 2);             // heavy first, 0..15
    const int h   = bh & (NH - 1);
    const int b   = bh >> 4;
    const size_t rowbase = (size_t)b * T_LEN;
    const int qrow = qbp * 128 + wave * 16;    // this wave's 16 q rows
    const int dt   = 2 * qbp + (wave >> 2);    // this wave's diagonal tile

    const float kQScale = 0.125f * 1.44269504088896f;
    bf16x8 ones;
    for (int j = 0; j < 8; j++) ones[j] = (__bf16)1.0f;

    // staging: 512 threads cover 64 keys x 8 chunks, one uint4 each
    const int key0 = tid >> 3, m8 = tid & 7;
    const __bf16* kp0 = qkv + (rowbase + key0) * 3072 + h * HD + m8 * 8 + 1024;
    const int pc0 = ((key0 >> 3) ^ m8) * 8 + (key0 & 7);

    bf16x8 qf[2];
    for (int ks = 0; ks < 2; ks++) {
        bf16x8 raw = *(const bf16x8*)&qkv[(rowbase + qrow + l16) * 3072
                                          + h * HD + ks * 32 + quad * 8];
        for (int j = 0; j < 8; j++)
            qf[ks][j] = (__bf16)((float)raw[j] * kQScale);
    }

    floatx4 o[4] = {}, ol = {};

    const int ntiles = 2 * qbp + 2;
    const size_t TSTEP = (size_t)64 * 3072;

    // prologue: tile 0 -> regs -> buf0 ; tile 1 -> regs ; barrier
    uint4 kr0 = *(const uint4*)kp0;
    uint4 vr0 = *(const uint4*)(kp0 + 1024);
    {
        *(uint4*)&sK[0][key0][m8 * 8] = kr0;
        bf16x8 v0 = *(bf16x8*)&vr0;
        for (int j = 0; j < 8; j++) sVt[0][m8 * 8 + j][pc0] = v0[j];
    }
    kr0 = *(const uint4*)(kp0 + TSTEP);            // ntiles >= 2 always
    vr0 = *(const uint4*)(kp0 + TSTEP + 1024);
    __syncthreads();

    for (int kt = 0; kt < ntiles; kt++) {
        const int cur = kt & 1, nxt = cur ^ 1;
        if (kt + 1 < ntiles) {
            *(uint4*)&sK[nxt][key0][m8 * 8] = kr0;
            bf16x8 v0 = *(bf16x8*)&vr0;
            for (int j = 0; j < 8; j++) sVt[nxt][m8 * 8 + j][pc0] = v0[j];
            size_t offn = (size_t)((kt + 2 < ntiles) ? kt + 2 : kt + 1) * TSTEP;
            kr0 = *(const uint4*)(kp0 + offn);
            vr0 = *(const uint4*)(kp0 + offn + 1024);
        }

        if (kt <= dt) {
            // S = Q K^T (exp2 domain) from buf[cur]
            floatx4 s_acc[4] = {};
            for (int jt = 0; jt < 4; jt++)
                for (int ks = 0; ks < 2; ks++) {
                    bf16x8 kf = *(const bf16x8*)&sK[cur][jt * 16 + l16]
                                                  [ks * 32 + quad * 8];
                    s_acc[jt] = __builtin_amdgcn_mfma_f32_16x16x32_bf16(
                        qf[ks], kf, s_acc[jt], 0, 0, 0);
                }

            // P = exp2(min(s,30)); mask only on this wave's diagonal tile.
            if (kt == dt) {
                const int tq0 = qrow + quad * 4;
                const int k0 = kt * 64;
                for (int jt = 0; jt < 4; jt++) {
                    int key = k0 + jt * 16 + l16;
                    for (int r = 0; r < 4; r++) {
                        float sv = (key <= tq0 + r) ? s_acc[jt][r] : -1e30f;
                        float pv = __builtin_amdgcn_exp2f(fminf(sv, 30.f));
                        sP[wave][quad * 4 + r][jt * 16 + l16] = (__bf16)pv;
                    }
                }
            } else {
                for (int jt = 0; jt < 4; jt++)
                    for (int r = 0; r < 4; r++) {
                        float pv = __builtin_amdgcn_exp2f(fminf(s_acc[jt][r], 30.f));
                        sP[wave][quad * 4 + r][jt * 16 + l16] = (__bf16)pv;
                    }
            }
            // sP wave-private: lgkmcnt ordering suffices, no barrier.

            for (int kp = 0; kp < 2; kp++) {
                bf16x8 pf = *(const bf16x8*)&sP[wave][l16][kp * 32 + quad * 8];
                ol = __builtin_amdgcn_mfma_f32_16x16x32_bf16(pf, ones, ol, 0, 0, 0);
                for (int jt2 = 0; jt2 < 4; jt2++) {
                    int d = jt2 * 16 + l16;
                    int pg = (kp * 4 + quad) ^ (d >> 3);
                    bf16x8 vf = *(const bf16x8*)&sVt[cur][d][pg * 8];
                    o[jt2] = __builtin_amdgcn_mfma_f32_16x16x32_bf16(
                        pf, vf, o[jt2], 0, 0, 0);
                }
            }
        }
        __syncthreads();   // all waves done reading cur & writing nxt
    }

    float inv[4];
    for (int r = 0; r < 4; r++) inv[r] = __builtin_amdgcn_rcpf(ol[r]);
    for (int jt2 = 0; jt2 < 4; jt2++) {
        for (int r = 0; r < 4; r++) {
            int tq  = qrow + quad * 4 + r;
            int col = h * HD + jt2 * 16 + l16;
            size_t gi = (rowbase + tq) * EMB + col;
            x2[gi] = x[gi] + o[jt2][r] * inv[r];
        }
    }
}

// ---------------------------------------------------------------------------
extern "C" void kernel_launch(void* const* d_in, const int* in_sizes, int n_in,
                              void* d_out, int out_size, void* d_ws, size_t ws_size,
                              hipStream_t stream) {
    const float* x      = (const float*)d_in[0];
    const float* ln1_s  = (const float*)d_in[1];
    const float* ln1_b  = (const float*)d_in[2];
    const float* w_qkv  = (const float*)d_in[3];
    const float* b_qkv  = (const float*)d_in[4];
    const float* ln2_s  = (const float*)d_in[5];
    const float* ln2_b  = (const float*)d_in[6];
    const float* w_fc   = (const float*)d_in[7];
    const float* b_fc   = (const float*)d_in[8];
    const float* w_proj = (const float*)d_in[9];
    const float* b_proj = (const float*)d_in[10];
    float* out = (float*)d_out;

    const int M = 2 * T_LEN;  // 4096 rows
    char* ws = (char*)d_ws;
    size_t off = 0;
    auto alloc = [&](size_t bytes) {
        void* p = ws + off; off += (bytes + 255) & ~(size_t)255; return p;
    };
    // alive through proj:
    __bf16* wpj_t  = (__bf16*)alloc((size_t)1024 * 4096 * 2);
    float*  x2     = (float*) alloc((size_t)M * 1024 * 4);
    __bf16* hfc    = (__bf16*)alloc((size_t)M * 4096 * 2);
    size_t mark = off;                    // dead-by-proj region starts here
    __bf16* wqkv_t = (__bf16*)alloc((size_t)3072 * 1024 * 2);
    __bf16* wfc_t  = (__bf16*)alloc((size_t)4096 * 1024 * 2);
    __bf16* h1     = (__bf16*)alloc((size_t)M * 1024 * 2);
    __bf16* h2     = (__bf16*)alloc((size_t)M * 1024 * 2);
    __bf16* qkvb   = (__bf16*)alloc((size_t)M * 3072 * 2);
    // split-K bf16 partials overlay the dead region.
    __bf16* pbuf = (__bf16*)(ws + mark);
    size_t need = mark + (size_t)4 * M * 1024 * 2;
    bool can_split = ws_size >= need;

    dim3 tb(32, 8);
    transpose_cast<<<dim3(3072 / 32, 1024 / 32), tb, 0, stream>>>(w_qkv, wqkv_t, 1024, 3072);
    transpose_cast<<<dim3(4096 / 32, 1024 / 32), tb, 0, stream>>>(w_fc,  wfc_t,  1024, 4096);
    transpose_cast<<<dim3(1024 / 32, 4096 / 32), tb, 0, stream>>>(w_proj, wpj_t, 4096, 1024);

    ln_kernel<<<M, 256, 0, stream>>>(x, ln1_s, ln1_b, h1);

    // qkv = LN1(x) @ w_qkv + b_qkv -> bf16 ; grid 16x12 flattened (192)
    gemm256<<<192, 512, 0, stream>>>(
        h1, wqkv_t, b_qkv, nullptr, nullptr, qkvb, M, 3072, 1024, 1024, 0,
        12, 1);

    attn_kernel<<<512, 512, 0, stream>>>(qkvb, x, x2);

    ln_kernel<<<M, 256, 0, stream>>>(x2, ln2_s, ln2_b, h2);

    // hfc = relu(h2 @ w_fc + b_fc) -> bf16 ; grid 16x16 flattened (256)
    gemm256<<<256, 512, 0, stream>>>(
        h2, wfc_t, b_fc, nullptr, nullptr, hfc, M, 4096, 1024, 1024, 1,
        16, 1);

    if (can_split) {
        // proj partials: 4 K-chunks of 1024, grid 16x4x4 flattened (256)
        gemm256<<<256, 512, 0, stream>>>(
            hfc, wpj_t, nullptr, nullptr, nullptr, pbuf, M, 1024, 4096, 1024, 0,
            4, 4);
        reduce_proj<<<(M * 1024 / 4) / 256, 256, 0, stream>>>(
            pbuf, x2, b_proj, out);
    } else {
        gemm_bt_n64<<<dim3(1024 / 64, M / 128), 256, 0, stream>>>(
            hfc, wpj_t, b_proj, x2, out, nullptr, M, 1024, 4096, 0);
    }
}

// Round 5
// 302.202 us; speedup vs baseline: 1.0227x; 1.0072x over previous
//
#include <hip/hip_runtime.h>
#include <hip/hip_bf16.h>

// ---------------------------------------------------------------------------
// Transformer block: x + attn(LN1(x)) ; then x2 + proj(relu(fc(LN2(x2))))
// B=2, T=2048, C=1024, H=16, hd=64, MLP hidden 4096. All GEMMs bf16 MFMA.
// R15: attn complementary-pair load balance. Block = (bh, pair): waves 0-3
//      own heavy q-tile qt_h (16..31), waves 4-7 own light q-tile 31-qt_h.
//      K-tile loop runs 0..qt_h; light group skips tiles past its diagonal
//      (wave-uniform branch, barriers outside). Per-block cost = 34 group-
//      tile units for EVERY block -> both resident blocks/CU live the whole
//      kernel (R14 failure mode: heavy blocks ran alone at 8 waves/CU).
//      Staging/softmax/PV/epilogue identical to R14. GEMMs unchanged.
// ---------------------------------------------------------------------------

typedef __bf16  bf16x8  __attribute__((ext_vector_type(8)));
typedef __bf16  bf16x4  __attribute__((ext_vector_type(4)));
typedef float   floatx4 __attribute__((ext_vector_type(4)));

#define T_LEN 2048
#define EMB   1024
#define NH    16
#define HD    64
#define HID   4096

#define GLOBAL_LOAD_LDS16(gp, lp) \
    __builtin_amdgcn_global_load_lds( \
        (const __attribute__((address_space(1))) void*)(gp), \
        (__attribute__((address_space(3))) void*)(lp), 16, 0, 0)

// ---------------- transpose + cast: in fp32 [R,C] -> out bf16 [C,R] --------
__global__ void transpose_cast(const float* __restrict__ in,
                               __bf16* __restrict__ out, int R, int C) {
    __shared__ float tile[32][33];
    int bc = blockIdx.x * 32;
    int br = blockIdx.y * 32;
    int tx = threadIdx.x;
    int ty = threadIdx.y;
    for (int i = 0; i < 32; i += 8) {
        tile[ty + i][tx] = in[(size_t)(br + ty + i) * C + bc + tx];
    }
    __syncthreads();
    for (int i = 0; i < 32; i += 8) {
        int c = bc + ty + i, r = br + tx;
        out[(size_t)c * R + r] = (__bf16)tile[tx][ty + i];
    }
}

// ---------------- layernorm fp32 [M,1024] -> bf16 [M,1024] -----------------
__global__ __launch_bounds__(256)
void ln_kernel(const float* __restrict__ in, const float* __restrict__ sc,
               const float* __restrict__ sh, __bf16* __restrict__ out) {
    int row = blockIdx.x;
    const float* p = in + (size_t)row * EMB;
    int tid = threadIdx.x;
    int lane = tid & 63, wave = tid >> 6;
    float v[4];
    float s = 0.f, s2 = 0.f;
    for (int j = 0; j < 4; j++) {
        v[j] = p[tid + j * 256];
        s += v[j]; s2 += v[j] * v[j];
    }
    for (int m = 1; m < 64; m <<= 1) {
        s  += __shfl_xor(s, m);
        s2 += __shfl_xor(s2, m);
    }
    __shared__ float ssum[4], ssum2[4];
    if (lane == 0) { ssum[wave] = s; ssum2[wave] = s2; }
    __syncthreads();
    float tot  = ssum[0] + ssum[1] + ssum[2] + ssum[3];
    float tot2 = ssum2[0] + ssum2[1] + ssum2[2] + ssum2[3];
    float mean = tot * (1.f / EMB);
    float var  = tot2 * (1.f / EMB) - mean * mean;
    float rstd = rsqrtf(var + 1e-5f);
    for (int j = 0; j < 4; j++) {
        int c = tid + j * 256;
        out[(size_t)row * EMB + c] = (__bf16)((v[j] - mean) * rstd * sc[c] + sh[c]);
    }
}

// ---------------- bf16 MFMA GEMM, BM=BN=256 BK=64, counted-vmcnt pipeline --
__global__ __launch_bounds__(512)
void gemm256(const __bf16* __restrict__ A, const __bf16* __restrict__ Bt,
             const float* __restrict__ bias, const float* __restrict__ res,
             float* __restrict__ outF, __bf16* __restrict__ outB,
             int M, int N, int lda, int KL, int relu, int gx, int gz) {
    __shared__ __align__(16) __bf16 sA[2][256][64];
    __shared__ __align__(16) __bf16 sB[2][256][64];
    const int BUFE = 256 * 64;
    int tid  = threadIdx.x;
    int lane = tid & 63, wave = tid >> 6;
    int quad = lane >> 4, l16 = lane & 15;

    // XCD swizzle decode: pair p=(by*gz+bz) pinned to XCD p&7. grid%8==0.
    int i  = blockIdx.x;
    int c  = i & 7, m = i >> 3;
    int bx = m % gx;
    int p  = (m / gx) * 8 + c;
    int by = p / gz;
    int bz = p - by * gz;

    int bm = by * 256, bn = bx * 256;
    size_t k0 = (size_t)bz * KL;
    int wm = (wave >> 2) * 128, wn = (wave & 3) * 64;

    floatx4 acc[8][4] = {};

    int srow  = tid >> 3;
    int sslot = (tid & 7) ^ (srow & 7);
    const __bf16* gA = A  + (size_t)(bm + srow) * lda + k0 + sslot * 8;
    const __bf16* gB = Bt + (size_t)(bn + srow) * lda + k0 + sslot * 8;
    __bf16* lA = &sA[0][0][0] + wave * 512;
    __bf16* lB = &sB[0][0][0] + wave * 512;
    const size_t rstep = (size_t)64 * lda;

#define STAGE256(nb, ko) do { \
    GLOBAL_LOAD_LDS16(gA + (ko),             lA + (nb) * BUFE); \
    GLOBAL_LOAD_LDS16(gB + (ko),             lB + (nb) * BUFE); \
    GLOBAL_LOAD_LDS16(gA + (ko) + rstep,     lA + (nb) * BUFE + 4096); \
    GLOBAL_LOAD_LDS16(gB + (ko) + rstep,     lB + (nb) * BUFE + 4096); \
    GLOBAL_LOAD_LDS16(gA + (ko) + 2 * rstep, lA + (nb) * BUFE + 8192); \
    GLOBAL_LOAD_LDS16(gB + (ko) + 2 * rstep, lB + (nb) * BUFE + 8192); \
    GLOBAL_LOAD_LDS16(gA + (ko) + 3 * rstep, lA + (nb) * BUFE + 12288); \
    GLOBAL_LOAD_LDS16(gB + (ko) + 3 * rstep, lB + (nb) * BUFE + 12288); \
} while (0)

    STAGE256(0, (size_t)0);

    int xs0  = ((quad) ^ (l16 & 7)) * 8;
    int xs1  = ((4 + quad) ^ (l16 & 7)) * 8;
    int aoff = (wm + l16) * 64;
    int boff = (wn + l16) * 64;

    const int nt = KL / 64;
    for (int t = 0; t < nt; ++t) {
        const int cur = t & 1;
        __builtin_amdgcn_s_barrier();          // all waves done reading buf^1
        asm volatile("" ::: "memory");
        if (t + 1 < nt) {
            STAGE256(cur ^ 1, (size_t)(t + 1) * 64);
            asm volatile("s_waitcnt vmcnt(8)" ::: "memory");  // tile t landed
        } else {
            asm volatile("s_waitcnt vmcnt(0)" ::: "memory");
        }
        __builtin_amdgcn_s_barrier();          // everyone's tile-t loads done
        asm volatile("" ::: "memory");
        __builtin_amdgcn_sched_barrier(0);

        const __bf16* sAc = &sA[0][0][0] + cur * BUFE;
        const __bf16* sBc = &sB[0][0][0] + cur * BUFE;

        bf16x8 a0[4][2], a1[4][2], b0[2][2], b1[2][2];

        // phase 1: A rows 0-63 (mi 0-3) + B cols 0-31 (nj 0-1)
        #pragma unroll
        for (int mi = 0; mi < 4; ++mi) {
            a0[mi][0] = *(const bf16x8*)(sAc + aoff + mi * 1024 + xs0);
            a0[mi][1] = *(const bf16x8*)(sAc + aoff + mi * 1024 + xs1);
        }
        #pragma unroll
        for (int nj = 0; nj < 2; ++nj) {
            b0[nj][0] = *(const bf16x8*)(sBc + boff + nj * 1024 + xs0);
            b0[nj][1] = *(const bf16x8*)(sBc + boff + nj * 1024 + xs1);
        }
        __builtin_amdgcn_s_setprio(1);
        #pragma unroll
        for (int ks = 0; ks < 2; ++ks)
            #pragma unroll
            for (int mi = 0; mi < 4; ++mi)
                #pragma unroll
                for (int nj = 0; nj < 2; ++nj)
                    acc[mi][nj] = __builtin_amdgcn_mfma_f32_16x16x32_bf16(
                        a0[mi][ks], b0[nj][ks], acc[mi][nj], 0, 0, 0);
        __builtin_amdgcn_s_setprio(0);

        // phase 2: load B cols 32-63 (nj 2-3); MFMA a0 x b1
        #pragma unroll
        for (int nj = 0; nj < 2; ++nj) {
            b1[nj][0] = *(const bf16x8*)(sBc + boff + (2 + nj) * 1024 + xs0);
            b1[nj][1] = *(const bf16x8*)(sBc + boff + (2 + nj) * 1024 + xs1);
        }
        __builtin_amdgcn_s_setprio(1);
        #pragma unroll
        for (int ks = 0; ks < 2; ++ks)
            #pragma unroll
            for (int mi = 0; mi < 4; ++mi)
                #pragma unroll
                for (int nj = 0; nj < 2; ++nj)
                    acc[mi][2 + nj] = __builtin_amdgcn_mfma_f32_16x16x32_bf16(
                        a0[mi][ks], b1[nj][ks], acc[mi][2 + nj], 0, 0, 0);
        __builtin_amdgcn_s_setprio(0);

        // phase 3: load A rows 64-127 (mi 4-7); MFMA a1 x b1
        #pragma unroll
        for (int mi = 0; mi < 4; ++mi) {
            a1[mi][0] = *(const bf16x8*)(sAc + aoff + (4 + mi) * 1024 + xs0);
            a1[mi][1] = *(const bf16x8*)(sAc + aoff + (4 + mi) * 1024 + xs1);
        }
        __builtin_amdgcn_s_setprio(1);
        #pragma unroll
        for (int ks = 0; ks < 2; ++ks)
            #pragma unroll
            for (int mi = 0; mi < 4; ++mi)
                #pragma unroll
                for (int nj = 0; nj < 2; ++nj)
                    acc[4 + mi][2 + nj] = __builtin_amdgcn_mfma_f32_16x16x32_bf16(
                        a1[mi][ks], b1[nj][ks], acc[4 + mi][2 + nj], 0, 0, 0);
        __builtin_amdgcn_s_setprio(0);

        // phase 4: MFMA a1 x b0 (no loads)
        __builtin_amdgcn_s_setprio(1);
        #pragma unroll
        for (int ks = 0; ks < 2; ++ks)
            #pragma unroll
            for (int mi = 0; mi < 4; ++mi)
                #pragma unroll
                for (int nj = 0; nj < 2; ++nj)
                    acc[4 + mi][nj] = __builtin_amdgcn_mfma_f32_16x16x32_bf16(
                        a1[mi][ks], b0[nj][ks], acc[4 + mi][nj], 0, 0, 0);
        __builtin_amdgcn_s_setprio(0);
    }
#undef STAGE256

    if (bias) {
        #pragma unroll
        for (int mi = 0; mi < 8; ++mi) {
            int row0 = bm + wm + mi * 16 + quad * 4;
            #pragma unroll
            for (int nj = 0; nj < 4; ++nj) {
                int col = bn + wn + nj * 16 + l16;
                float bv = bias[col];
                #pragma unroll
                for (int r = 0; r < 4; ++r) {
                    size_t idx = (size_t)(row0 + r) * N + col;
                    float cc = acc[mi][nj][r] + bv;
                    if (relu) cc = fmaxf(cc, 0.f);
                    if (res)  cc += res[idx];
                    if (outF) outF[idx] = cc;
                    if (outB) outB[idx] = (__bf16)cc;
                }
            }
        }
    } else {
        __bf16* po = outB + (size_t)bz * M * N;
        #pragma unroll
        for (int mi = 0; mi < 8; ++mi) {
            int row0 = bm + wm + mi * 16 + quad * 4;
            #pragma unroll
            for (int nj = 0; nj < 4; ++nj) {
                int col = bn + wn + nj * 16 + l16;
                #pragma unroll
                for (int r = 0; r < 4; ++r)
                    po[(size_t)(row0 + r) * N + col] = (__bf16)acc[mi][nj][r];
            }
        }
    }
}

// ---------------- split-K reduce: out = x2 + bias + sum of 4 bf16 partials -
__global__ __launch_bounds__(256)
void reduce_proj(const __bf16* __restrict__ pbuf, const float* __restrict__ x2,
                 const float* __restrict__ bias, float* __restrict__ out) {
    const size_t MN = (size_t)4096 * 1024;
    size_t i = (size_t)blockIdx.x * 256 + threadIdx.x;   // float4 index
    float4 r = ((const float4*)x2)[i];
    float4 bb = ((const float4*)bias)[i & 255];
    float acc0 = r.x + bb.x, acc1 = r.y + bb.y;
    float acc2 = r.z + bb.z, acc3 = r.w + bb.w;
    for (int k = 0; k < 4; k++) {
        bf16x4 pv = *(const bf16x4*)&pbuf[k * MN + i * 4];
        acc0 += (float)pv[0]; acc1 += (float)pv[1];
        acc2 += (float)pv[2]; acc3 += (float)pv[3];
    }
    float4 o = {acc0, acc1, acc2, acc3};
    ((float4*)out)[i] = o;
}

// ---------------- bf16 MFMA GEMM (BM=128, BN=64) — ws-fallback only --------
__global__ __launch_bounds__(256)
void gemm_bt_n64(const __bf16* __restrict__ A, const __bf16* __restrict__ Bt,
                 const float* __restrict__ bias, const float* __restrict__ res,
                 float* __restrict__ outF, __bf16* __restrict__ outB,
                 int M, int N, int K, int relu) {
    __shared__ __align__(16) __bf16 sA[128][40];
    __shared__ __align__(16) __bf16 sB[64][40];
    int tid  = threadIdx.x;
    int lane = tid & 63, wave = tid >> 6;
    int quad = lane >> 4, l16 = lane & 15;
    int bm = blockIdx.y * 128, bn = blockIdx.x * 64;
    int wm = (wave & 1) * 64, wn = (wave >> 1) * 32;
    floatx4 acc[4][2] = {};

    int srow = tid >> 2;
    int scol = (tid & 3) * 8;
    const __bf16* gA = &A[(size_t)(bm + srow) * K + scol];
    const __bf16* gB = &Bt[(size_t)(bn + srow) * K + scol];

    uint4 ra0 = *(const uint4*)gA;
    uint4 ra1 = *(const uint4*)(gA + (size_t)64 * K);
    uint4 rb0 = *(const uint4*)gB;

    for (int kk = 0; kk < K; kk += 32) {
        __syncthreads();
        *(uint4*)&sA[srow][scol]      = ra0;
        *(uint4*)&sA[srow + 64][scol] = ra1;
        *(uint4*)&sB[srow][scol]      = rb0;
        __syncthreads();
        {
            int kn = (kk + 32 < K) ? kk + 32 : kk;
            ra0 = *(const uint4*)(gA + kn);
            ra1 = *(const uint4*)(gA + kn + (size_t)64 * K);
            rb0 = *(const uint4*)(gB + kn);
        }
        bf16x8 af[4], bfr[2];
        for (int i = 0; i < 4; i++)
            af[i] = *(const bf16x8*)&sA[wm + i * 16 + l16][quad * 8];
        for (int j = 0; j < 2; j++)
            bfr[j] = *(const bf16x8*)&sB[wn + j * 16 + l16][quad * 8];
        for (int i = 0; i < 4; i++)
            for (int j = 0; j < 2; j++)
                acc[i][j] = __builtin_amdgcn_mfma_f32_16x16x32_bf16(
                    af[i], bfr[j], acc[i][j], 0, 0, 0);
    }

    for (int i = 0; i < 4; i++) {
        int row0 = bm + wm + i * 16 + quad * 4;
        for (int j = 0; j < 2; j++) {
            int col = bn + wn + j * 16 + l16;
            float bv = bias[col];
            for (int r = 0; r < 4; r++) {
                size_t idx = (size_t)(row0 + r) * N + col;
                float c = acc[i][j][r] + bv;
                if (relu) c = fmaxf(c, 0.f);
                if (res)  c += res[idx];
                if (outF) outF[idx] = c;
                if (outB) outB[idx] = (__bf16)c;
            }
        }
    }
}

// ---------------- flash attention: complementary-pair balanced blocks ------
// grid 512: i -> XCD c=i&7, m=i>>3; bh=(m&3)*8+c (pinned to XCD);
// pair = m>>2 (0..15): heavy q-tile qt_h = 31-pair (16..31), light q-tile
// qt_l = 31-qt_h (0..15). Waves 0-3 own qt_h rows, waves 4-7 own qt_l rows
// (16 rows/wave). K-tile loop 0..qt_h; a wave group skips tiles past its
// diagonal (wave-uniform, barriers outside). Every block = 34 group-tile
// units -> perfect balance. Softmax: P = exp2(min(s,30)) fixed-max,
// wave-private sP (no mid barrier). l via ones-MFMA; epilogue divides.
__global__ __launch_bounds__(512)
void attn_kernel(const __bf16* __restrict__ qkv, const float* __restrict__ x,
                 float* __restrict__ x2) {
    __shared__ __align__(16) __bf16 sK[2][64][72];
    __shared__ __align__(16) __bf16 sVt[2][64][72];
    __shared__ __align__(16) __bf16 sP[8][16][72];
    const int tid  = threadIdx.x;
    const int lane = tid & 63, wave = tid >> 6;
    const int quad = lane >> 4, l16 = lane & 15;

    int i = blockIdx.x;
    int c = i & 7, m = i >> 3;
    const int bh   = (m & 3) * 8 + c;          // 0..31, XCD-pinned
    const int qt_h = 31 - (m >> 2);            // heavy q-tile, 16..31
    const int h    = bh & (NH - 1);
    const int b    = bh >> 4;
    const size_t rowbase = (size_t)b * T_LEN;

    const int g  = wave >> 2;                  // 0 = heavy group, 1 = light
    const int wg = wave & 3;
    const int qt = g ? (31 - qt_h) : qt_h;     // this group's q-tile
    const int qrow = qt * 64 + wg * 16;        // this wave's 16 q rows
    const int dt   = qt;                       // group's diagonal K-tile

    const float kQScale = 0.125f * 1.44269504088896f;
    bf16x8 ones;
    for (int j = 0; j < 8; j++) ones[j] = (__bf16)1.0f;

    // staging: 512 threads cover 64 keys x 8 chunks, one uint4 each
    const int key0 = tid >> 3, m8 = tid & 7;
    const __bf16* kp0 = qkv + (rowbase + key0) * 3072 + h * HD + m8 * 8 + 1024;
    const int pc0 = ((key0 >> 3) ^ m8) * 8 + (key0 & 7);

    bf16x8 qf[2];
    for (int ks = 0; ks < 2; ks++) {
        bf16x8 raw = *(const bf16x8*)&qkv[(rowbase + qrow + l16) * 3072
                                          + h * HD + ks * 32 + quad * 8];
        for (int j = 0; j < 8; j++)
            qf[ks][j] = (__bf16)((float)raw[j] * kQScale);
    }

    floatx4 o[4] = {}, ol = {};

    const int ntiles = qt_h + 1;               // 17..32
    const size_t TSTEP = (size_t)64 * 3072;

    // prologue: tile 0 -> regs -> buf0 ; tile 1 -> regs ; barrier
    uint4 kr0 = *(const uint4*)kp0;
    uint4 vr0 = *(const uint4*)(kp0 + 1024);
    {
        *(uint4*)&sK[0][key0][m8 * 8] = kr0;
        bf16x8 v0 = *(bf16x8*)&vr0;
        for (int j = 0; j < 8; j++) sVt[0][m8 * 8 + j][pc0] = v0[j];
    }
    kr0 = *(const uint4*)(kp0 + TSTEP);            // ntiles >= 17 always
    vr0 = *(const uint4*)(kp0 + TSTEP + 1024);
    __syncthreads();

    for (int kt = 0; kt < ntiles; kt++) {
        const int cur = kt & 1, nxt = cur ^ 1;
        if (kt + 1 < ntiles) {
            *(uint4*)&sK[nxt][key0][m8 * 8] = kr0;
            bf16x8 v0 = *(bf16x8*)&vr0;
            for (int j = 0; j < 8; j++) sVt[nxt][m8 * 8 + j][pc0] = v0[j];
            size_t offn = (size_t)((kt + 2 < ntiles) ? kt + 2 : kt + 1) * TSTEP;
            kr0 = *(const uint4*)(kp0 + offn);
            vr0 = *(const uint4*)(kp0 + offn + 1024);
        }

        if (kt <= dt) {
            // S = Q K^T (exp2 domain) from buf[cur]
            floatx4 s_acc[4] = {};
            for (int jt = 0; jt < 4; jt++)
                for (int ks = 0; ks < 2; ks++) {
                    bf16x8 kf = *(const bf16x8*)&sK[cur][jt * 16 + l16]
                                                  [ks * 32 + quad * 8];
                    s_acc[jt] = __builtin_amdgcn_mfma_f32_16x16x32_bf16(
                        qf[ks], kf, s_acc[jt], 0, 0, 0);
                }

            // P = exp2(min(s,30)); mask only on this group's diagonal tile.
            if (kt == dt) {
                const int tq0 = qrow + quad * 4;
                const int k0 = kt * 64;
                for (int jt = 0; jt < 4; jt++) {
                    int key = k0 + jt * 16 + l16;
                    for (int r = 0; r < 4; r++) {
                        float sv = (key <= tq0 + r) ? s_acc[jt][r] : -1e30f;
                        float pv = __builtin_amdgcn_exp2f(fminf(sv, 30.f));
                        sP[wave][quad * 4 + r][jt * 16 + l16] = (__bf16)pv;
                    }
                }
            } else {
                for (int jt = 0; jt < 4; jt++)
                    for (int r = 0; r < 4; r++) {
                        float pv = __builtin_amdgcn_exp2f(fminf(s_acc[jt][r], 30.f));
                        sP[wave][quad * 4 + r][jt * 16 + l16] = (__bf16)pv;
                    }
            }
            // sP wave-private: lgkmcnt ordering suffices, no barrier.

            for (int kp = 0; kp < 2; kp++) {
                bf16x8 pf = *(const bf16x8*)&sP[wave][l16][kp * 32 + quad * 8];
                ol = __builtin_amdgcn_mfma_f32_16x16x32_bf16(pf, ones, ol, 0, 0, 0);
                for (int jt2 = 0; jt2 < 4; jt2++) {
                    int d = jt2 * 16 + l16;
                    int pg = (kp * 4 + quad) ^ (d >> 3);
                    bf16x8 vf = *(const bf16x8*)&sVt[cur][d][pg * 8];
                    o[jt2] = __builtin_amdgcn_mfma_f32_16x16x32_bf16(
                        pf, vf, o[jt2], 0, 0, 0);
                }
            }
        }
        __syncthreads();   // all waves done reading cur & writing nxt
    }

    float inv[4];
    for (int r = 0; r < 4; r++) inv[r] = __builtin_amdgcn_rcpf(ol[r]);
    for (int jt2 = 0; jt2 < 4; jt2++) {
        for (int r = 0; r < 4; r++) {
            int tq  = qrow + quad * 4 + r;
            int col = h * HD + jt2 * 16 + l16;
            size_t gi = (rowbase + tq) * EMB + col;
            x2[gi] = x[gi] + o[jt2][r] * inv[r];
        }
    }
}

// ---------------------------------------------------------------------------
extern "C" void kernel_launch(void* const* d_in, const int* in_sizes, int n_in,
                              void* d_out, int out_size, void* d_ws, size_t ws_size,
                              hipStream_t stream) {
    const float* x      = (const float*)d_in[0];
    const float* ln1_s  = (const float*)d_in[1];
    const float* ln1_b  = (const float*)d_in[2];
    const float* w_qkv  = (const float*)d_in[3];
    const float* b_qkv  = (const float*)d_in[4];
    const float* ln2_s  = (const float*)d_in[5];
    const float* ln2_b  = (const float*)d_in[6];
    const float* w_fc   = (const float*)d_in[7];
    const float* b_fc   = (const float*)d_in[8];
    const float* w_proj = (const float*)d_in[9];
    const float* b_proj = (const float*)d_in[10];
    float* out = (float*)d_out;

    const int M = 2 * T_LEN;  // 4096 rows
    char* ws = (char*)d_ws;
    size_t off = 0;
    auto alloc = [&](size_t bytes) {
        void* p = ws + off; off += (bytes + 255) & ~(size_t)255; return p;
    };
    // alive through proj:
    __bf16* wpj_t  = (__bf16*)alloc((size_t)1024 * 4096 * 2);
    float*  x2     = (float*) alloc((size_t)M * 1024 * 4);
    __bf16* hfc    = (__bf16*)alloc((size_t)M * 4096 * 2);
    size_t mark = off;                    // dead-by-proj region starts here
    __bf16* wqkv_t = (__bf16*)alloc((size_t)3072 * 1024 * 2);
    __bf16* wfc_t  = (__bf16*)alloc((size_t)4096 * 1024 * 2);
    __bf16* h1     = (__bf16*)alloc((size_t)M * 1024 * 2);
    __bf16* h2     = (__bf16*)alloc((size_t)M * 1024 * 2);
    __bf16* qkvb   = (__bf16*)alloc((size_t)M * 3072 * 2);
    // split-K bf16 partials overlay the dead region.
    __bf16* pbuf = (__bf16*)(ws + mark);
    size_t need = mark + (size_t)4 * M * 1024 * 2;
    bool can_split = ws_size >= need;

    dim3 tb(32, 8);
    transpose_cast<<<dim3(3072 / 32, 1024 / 32), tb, 0, stream>>>(w_qkv, wqkv_t, 1024, 3072);
    transpose_cast<<<dim3(4096 / 32, 1024 / 32), tb, 0, stream>>>(w_fc,  wfc_t,  1024, 4096);
    transpose_cast<<<dim3(1024 / 32, 4096 / 32), tb, 0, stream>>>(w_proj, wpj_t, 4096, 1024);

    ln_kernel<<<M, 256, 0, stream>>>(x, ln1_s, ln1_b, h1);

    // qkv = LN1(x) @ w_qkv + b_qkv -> bf16 ; grid 16x12 flattened (192)
    gemm256<<<192, 512, 0, stream>>>(
        h1, wqkv_t, b_qkv, nullptr, nullptr, qkvb, M, 3072, 1024, 1024, 0,
        12, 1);

    attn_kernel<<<512, 512, 0, stream>>>(qkvb, x, x2);

    ln_kernel<<<M, 256, 0, stream>>>(x2, ln2_s, ln2_b, h2);

    // hfc = relu(h2 @ w_fc + b_fc) -> bf16 ; grid 16x16 flattened (256)
    gemm256<<<256, 512, 0, stream>>>(
        h2, wfc_t, b_fc, nullptr, nullptr, hfc, M, 4096, 1024, 1024, 1,
        16, 1);

    if (can_split) {
        // proj partials: 4 K-chunks of 1024, grid 16x4x4 flattened (256)
        gemm256<<<256, 512, 0, stream>>>(
            hfc, wpj_t, nullptr, nullptr, nullptr, pbuf, M, 1024, 4096, 1024, 0,
            4, 4);
        reduce_proj<<<(M * 1024 / 4) / 256, 256, 0, stream>>>(
            pbuf, x2, b_proj, out);
    } else {
        gemm_bt_n64<<<dim3(1024 / 64, M / 128), 256, 0, stream>>>(
            hfc, wpj_t, b_proj, x2, out, nullptr, M, 1024, 4096, 0);
    }
}